// Round 9
// baseline (442.114 us; speedup 1.0000x reference)
//
#include <hip/hip_runtime.h>
#include <stdint.h>

#define NPIX 6084      // 78*78 pixels / patches
#define NPAD 6144      // padded to 48*128 (= 24*256)
#define KDIM 2304      // 256*3*3
#define KB   (KDIM*2)  // row bytes in bf16 = 4608
#define NT   36        // K-tiles of 64

typedef __attribute__((ext_vector_type(8))) short s16x8;
typedef __attribute__((ext_vector_type(4))) float f32x4;

__device__ __forceinline__ short f2bf(float f) {
  unsigned u = __builtin_bit_cast(unsigned, f);
  u += 0x7FFFu + ((u >> 16) & 1u);
  return (short)(u >> 16);
}
__device__ __forceinline__ float bf2f(short s) {
  unsigned u = ((unsigned)(unsigned short)s) << 16;
  return __builtin_bit_cast(float, u);
}

#define GL16(g, l)                                                            \
  __builtin_amdgcn_global_load_lds(                                           \
      (__attribute__((address_space(1))) unsigned int*)(g),                   \
      (__attribute__((address_space(3))) unsigned int*)(l), 16, 0, 0)

// ---------------- prep: cast patches f32 -> bf16, pad rows to 6144 ----------
__global__ __launch_bounds__(256) void k_prep_pat(const float* __restrict__ pat,
                                                  short* __restrict__ out) {
  int i = blockIdx.x * 256 + threadIdx.x;  // one 8-elem chunk
  int e0 = i * 8;
  int row = e0 / KDIM;
  s16x8 v;
  if (row < NPIX) {
    const float* s = pat + e0;
#pragma unroll
    for (int j = 0; j < 8; ++j) v[j] = f2bf(s[j]);
  } else {
#pragma unroll
    for (int j = 0; j < 8; ++j) v[j] = 0;
  }
  *(s16x8*)(out + e0) = v;
}

// ------- im2col v2: LDS-staged, coalesced reads AND writes ------------------
// block b<624: (p = b>>3, cc = b&7): stage x[cc*32..+32][p..p+2][0..79] (30KB)
// then write xcol rows m=p*78..+77, k-cols cc*288..+287. Blocks 624..631 zero
// the pad rows 6084..6143.
__global__ __launch_bounds__(256) void k_xcol2(const float* __restrict__ x,
                                               short* __restrict__ out) {
  __shared__ float lx[7680];  // [32 ch][3 rows][80 cols]
  const int b = blockIdx.x, tid = threadIdx.x;
  if (b >= 624) {  // zero pad rows
    int i = b - 624;
    s16x8 z = {};
#pragma unroll
    for (int it = 0; it < 9; ++it) {
      int t = i * 2160 + it * 256 + tid;  // 8*2160 = 17280 chunks exactly
      if (t < 17280) ((s16x8*)out)[(size_t)NPIX * KDIM / 8 + t] = z;
    }
    return;
  }
  const int p = b >> 3, cc = b & 7;
  for (int t = tid; t < 7680; t += 256) {
    int ci = t / 240, rr = t - ci * 240;
    lx[t] = x[(cc * 32 + ci) * 6400 + p * 80 + rr];
  }
  __syncthreads();
  for (int t = tid; t < 22464; t += 256) {  // 78 q * 288 e
    int q = t / 288, e = t - q * 288;
    int ci = e / 9, r = e - ci * 9;
    int dy = r / 3, dx = r - dy * 3;
    out[(size_t)(p * 78 + q) * KDIM + cc * 288 + e] =
        f2bf(lx[ci * 240 + dy * 80 + q + dx]);
  }
}

// ---------------- GEMM: 256x256 tile, BK=64, 8-phase counted-vmcnt ----------
// T3+T4 (vmcnt(6) at P4/P8 only) + T2 (3-bit XOR swizzle) + T5 (setprio).
// NEW: epilogue also emits per-(row, tn-block) f32 max + argcol into
// gval/gidx [24][6144] so argmax never rescans the 75MB sim.
__global__ __launch_bounds__(512, 2) void k_gemm(const short* __restrict__ A,
                                                 const short* __restrict__ B,
                                                 short* __restrict__ C,
                                                 float* __restrict__ gval,
                                                 int* __restrict__ gidx) {
  __shared__ __align__(1024) char smem[131072];  // [par][A 32K | B 32K]
  const int tid = threadIdx.x;
  const int w = tid >> 6, lane = tid & 63;
  const int wr = w >> 2, wc = w & 3;  // 2M x 4N
  const int tm = blockIdx.y, tn = blockIdx.x;
  const char* Ab = (const char*)A + (size_t)tm * 256 * KB;
  const char* Bb = (const char*)B + (size_t)tn * 256 * KB;

  const int srccol = ((lane & 7) * 16) ^ ((lane >> 3) << 4);
  const int lrow = lane >> 3;
  const int fragRow = lane & 15;
  const int swz = (lane & 7) << 4;
  const int colb0 = (lane >> 4) * 16;
  const int aOff = (wr * 128 + fragRow) * 128;
  const int bOff = 32768 + (wc * 64 + fragRow) * 128;

  f32x4 acc[8][4] = {};
  s16x8 a[4][2];
  s16x8 b[2][2][2];

#define STAGE_A(par, hs, kt)                                                  \
  _Pragma("unroll") for (int j = 0; j < 2; ++j) {                             \
    int c = w * 2 + j;                                                        \
    int rb = (c < 8) ? (hs)*64 + c * 8 : 128 + (hs)*64 + (c - 8) * 8;         \
    GL16(Ab + (size_t)(rb + lrow) * KB + (kt)*128 + srccol,                   \
         smem + (par)*65536 + rb * 128);                                      \
  }
#define STAGE_B(par, hs, kt)                                                  \
  _Pragma("unroll") for (int j = 0; j < 2; ++j) {                             \
    int c = w * 2 + j;                                                        \
    int rb = (c >> 2) * 64 + (hs)*32 + (c & 3) * 8;                           \
    GL16(Bb + (size_t)(rb + lrow) * KB + (kt)*128 + srccol,                   \
         smem + (par)*65536 + 32768 + rb * 128);                              \
  }
#define LDA(par, mh)                                                          \
  _Pragma("unroll") for (int mi2 = 0; mi2 < 4; ++mi2)                         \
  _Pragma("unroll") for (int ks = 0; ks < 2; ++ks)                            \
    a[mi2][ks] = *(const s16x8*)(smem + (par)*65536 + aOff + (mh)*8192 +      \
                                 mi2 * 2048 + ((colb0 + ks * 64) ^ swz));
#define LDB(par, nh)                                                          \
  _Pragma("unroll") for (int ni2 = 0; ni2 < 2; ++ni2)                         \
  _Pragma("unroll") for (int ks = 0; ks < 2; ++ks)                            \
    b[nh][ni2][ks] = *(const s16x8*)(smem + (par)*65536 + bOff + (nh)*4096 +  \
                                     ni2 * 2048 + ((colb0 + ks * 64) ^ swz));
#define VM6() asm volatile("s_waitcnt vmcnt(6)" ::: "memory")
#define BAR() asm volatile("s_barrier" ::: "memory")
#define BARL() asm volatile("s_barrier\n\ts_waitcnt lgkmcnt(0)" ::: "memory")
#define QM(mh, nh)                                                            \
  do {                                                                        \
    __builtin_amdgcn_s_setprio(1);                                            \
    _Pragma("unroll") for (int mi2 = 0; mi2 < 4; ++mi2)                       \
    _Pragma("unroll") for (int ni2 = 0; ni2 < 2; ++ni2)                       \
    _Pragma("unroll") for (int ks = 0; ks < 2; ++ks)                          \
      acc[(mh)*4 + mi2][(nh)*2 + ni2] =                                       \
          __builtin_amdgcn_mfma_f32_16x16x32_bf16(                            \
              a[mi2][ks], b[nh][ni2][ks], acc[(mh)*4 + mi2][(nh)*2 + ni2],    \
              0, 0, 0);                                                       \
    __builtin_amdgcn_s_setprio(0);                                            \
    BAR();                                                                    \
  } while (0)

  STAGE_A(0, 0, 0); STAGE_B(0, 0, 0); STAGE_B(0, 1, 0); STAGE_A(0, 1, 0);
  STAGE_A(1, 0, 1); STAGE_B(1, 0, 1); STAGE_B(1, 1, 1);
  VM6();
  BAR();

#pragma unroll 1
  for (int i = 0; i < NT / 2; ++i) {
    const int t2 = (2 * i + 2 < NT) ? 2 * i + 2 : NT - 1;
    const int t3 = (2 * i + 3 < NT) ? 2 * i + 3 : NT - 1;
    LDA(0, 0); LDB(0, 0);
    STAGE_A(1, 1, 2 * i + 1);
    BARL(); QM(0, 0);
    LDB(0, 1);
    STAGE_A(0, 0, t2);
    BARL(); QM(0, 1);
    LDA(0, 1);
    STAGE_B(0, 0, t2);
    BARL(); QM(1, 1);
    STAGE_B(0, 1, t2);
    VM6();
    BARL(); QM(1, 0);
    LDA(1, 0); LDB(1, 0);
    STAGE_A(0, 1, t2);
    BARL(); QM(0, 0);
    LDB(1, 1);
    STAGE_A(1, 0, t3);
    BARL(); QM(0, 1);
    LDA(1, 1);
    STAGE_B(1, 0, t3);
    BARL(); QM(1, 1);
    STAGE_B(1, 1, t3);
    VM6();
    BARL(); QM(1, 0);
  }

  // epilogue 1: write bf16 sim
  const int rowb = tm * 256 + wr * 128 + (lane >> 4) * 4;
  const int colb = tn * 256 + wc * 64 + (lane & 15);
#pragma unroll
  for (int mi = 0; mi < 8; ++mi)
#pragma unroll
    for (int ni = 0; ni < 4; ++ni)
#pragma unroll
      for (int j = 0; j < 4; ++j)
        C[(size_t)(rowb + mi * 16 + j) * NPAD + colb + ni * 16] =
            f2bf(acc[mi][ni][j]);

  // epilogue 2: per-row block max (excluding padded cols >= NPIX)
  float* tval = (float*)smem;          // [256][4]
  int* tcol = (int*)(smem + 4096);     // [256][4]
#pragma unroll
  for (int mi = 0; mi < 8; ++mi)
#pragma unroll
    for (int j = 0; j < 4; ++j) {
      float bv = -1e30f;
      int bc = 0x7FFFFFFF;
#pragma unroll
      for (int ni = 0; ni < 4; ++ni) {
        int cg = colb + ni * 16;
        float v = (cg < NPIX) ? acc[mi][ni][j] : -1e30f;
        if (v > bv || (v == bv && cg < bc)) { bv = v; bc = cg; }
      }
#pragma unroll
      for (int off = 1; off < 16; off <<= 1) {
        float ov = __shfl_xor(bv, off);
        int oc = __shfl_xor(bc, off);
        if (ov > bv || (ov == bv && oc < bc)) { bv = ov; bc = oc; }
      }
      if ((lane & 15) == 0) {
        int rloc = wr * 128 + mi * 16 + (lane >> 4) * 4 + j;
        tval[rloc * 4 + wc] = bv;
        tcol[rloc * 4 + wc] = bc;
      }
    }
  __syncthreads();
  if (tid < 256) {
    float bv = tval[tid * 4];
    int bc = tcol[tid * 4];
#pragma unroll
    for (int t = 1; t < 4; ++t) {
      float v = tval[tid * 4 + t];
      int c2 = tcol[tid * 4 + t];
      if (v > bv || (v == bv && c2 < bc)) { bv = v; bc = c2; }
    }
    gval[tn * NPAD + tm * 256 + tid] = bv;
    gidx[tn * NPAD + tm * 256 + tid] = bc;
  }
}

// ------- argmax v2: reduce 24 block-maxes, lazy sim read, f64 rescore -------
__global__ __launch_bounds__(256) void k_argmax2(const short* __restrict__ sim,
                                                 const float* __restrict__ gval,
                                                 const int* __restrict__ gidx,
                                                 const float* __restrict__ x,
                                                 const float* __restrict__ pat,
                                                 int* __restrict__ amax) {
  __shared__ int cand[4][32];
  __shared__ int ccnt[4];
  const int tid = threadIdx.x, w = tid >> 6, lane = tid & 63;
  const int pix = blockIdx.x * 4 + w;  // 1521*4 = 6084 exact

  float v0 = (lane < 24) ? gval[lane * NPAD + pix] : -1e30f;
  int c0 = (lane < 24) ? gidx[lane * NPAD + pix] : 0x7FFFFFFF;
  float v = v0;
  int c = c0;
  for (int off = 32; off; off >>= 1) {
    float ov = __shfl_down(v, off);
    int oc = __shfl_down(c, off);
    if (ov > v || (ov == v && oc < c)) { v = ov; c = oc; }
  }
  const float maxv = __shfl(v, 0);
  const int bestc = __shfl(c, 0);

  if (lane == 0) ccnt[w] = 0;
  __syncthreads();

  const float thrb = maxv - 4.0f;
  for (int t = 0; t < 24; ++t) {
    float bm = __shfl(v0, t);
    if (bm >= thrb) {
      short4 s4 = *(const short4*)(sim + (size_t)pix * NPAD + t * 256 + lane * 4);
#pragma unroll
      for (int j = 0; j < 4; ++j) {
        int k = t * 256 + lane * 4 + j;
        float f = bf2f(((const short*)&s4)[j]);
        if (f >= thrb - 0.6f && k < NPIX) {
          int pos = atomicAdd(&ccnt[w], 1);
          if (pos < 32) cand[w][pos] = k;
        }
      }
    }
  }
  __syncthreads();

  int n = ccnt[w] < 32 ? ccnt[w] : 32;
  if (n <= 1) {
    if (lane == 0) amax[pix] = bestc;
    return;
  }
  const int p = pix / 78, q = pix - (pix / 78) * 78;
  double bests = -1e300;
  int bestk = 0;
  for (int ci = 0; ci < n; ++ci) {
    int k = cand[w][ci];
    double s = 0.0;
    for (int cc = lane; cc < 256; cc += 64) {
      const float* xb = x + cc * 6400 + p * 80 + q;
      const float* pb = pat + (size_t)k * KDIM + cc * 9;
#pragma unroll
      for (int dy = 0; dy < 3; ++dy)
#pragma unroll
        for (int dx = 0; dx < 3; ++dx)
          s += (double)xb[dy * 80 + dx] * (double)pb[dy * 3 + dx];
    }
    for (int off = 32; off; off >>= 1) s += __shfl_down(s, off);
    if (lane == 0 && (s > bests || (s == bests && k < bestk))) {
      bests = s; bestk = k;
    }
  }
  if (lane == 0) amax[pix] = bestk;
}

// ------- scatter9: collision-free scatter into 9 shift planes ---------------
__global__ __launch_bounds__(256) void k_scat9(const float* __restrict__ pat,
                                               const int* __restrict__ amax,
                                               float* __restrict__ plane) {
  __shared__ float lp[KDIM];
  const int b = blockIdx.x;            // 6084 source pixels
  const int k = amax[b];
  const int p = b / 78, q = b - (b / 78) * 78;
  const float* src = pat + (size_t)k * KDIM;
#pragma unroll
  for (int j = 0; j < 9; ++j) lp[j * 256 + threadIdx.x] = src[j * 256 + threadIdx.x];
  __syncthreads();
  const int c = threadIdx.x;
#pragma unroll
  for (int r = 0; r < 9; ++r) {
    int dy = r / 3, dx = r - dy * 3;
    int pos = (p + dy) * 80 + (q + dx);   // always in [0,6400)
    plane[(size_t)r * 1638400 + pos * 256 + c] = lp[c * 9 + r];
  }
}

// ------- reduce: out[c][pix] = sum over valid planes / analytic count -------
__global__ __launch_bounds__(256) void k_reduce(const float* __restrict__ plane,
                                                float* __restrict__ out) {
  const int c = threadIdx.x;
  const int pix0 = blockIdx.x * 16;
  for (int i = 0; i < 16; ++i) {
    int pix = pix0 + i;
    int yy = pix / 80, xx = pix - (pix / 80) * 80;
    float s = 0.f;
    int cnt = 0;
#pragma unroll
    for (int r = 0; r < 9; ++r) {
      int dy = r / 3, dx = r - dy * 3;
      int p = yy - dy, q = xx - dx;
      if (p >= 0 && p < 78 && q >= 0 && q < 78) {
        s += plane[(size_t)r * 1638400 + pix * 256 + c];
        ++cnt;
      }
    }
    out[c * 6400 + pix] = s / (float)cnt;
  }
}

extern "C" void kernel_launch(void* const* d_in, const int* in_sizes, int n_in,
                              void* d_out, int out_size, void* d_ws,
                              size_t ws_size, hipStream_t stream) {
  const float* x = (const float*)d_in[0];    // (1,256,80,80) f32
  const float* pat = (const float*)d_in[1];  // (6084,256,3,3) f32
  float* out = (float*)d_out;                // (1,256,80,80) f32
  char* ws = (char*)d_ws;

  short* patB = (short*)ws;                          // 28,311,552 B
  short* xcol = (short*)(ws + 28311552);             // 28,311,552 B
  short* sim  = (short*)(ws + 2 * 28311552);         // 75,497,472 B
  float* plane = (float*)sim;                        // 58,982,400 B (overlays dead sim)
  int*   amax = (int*)(ws + 132120576);              // 24,336 B
  float* gval = (float*)(ws + 132144912);            // 589,824 B
  int*   gidx = (int*)(ws + 132734736);              // 589,824 B (ends 127.2 MiB)

  k_prep_pat<<<6912, 256, 0, stream>>>(pat, patB);
  k_xcol2<<<632, 256, 0, stream>>>(x, xcol);
  k_gemm<<<dim3(24, 24), 512, 0, stream>>>(xcol, patB, sim, gval, gidx);
  k_argmax2<<<1521, 256, 0, stream>>>(sim, gval, gidx, x, pat, amax);
  k_scat9<<<6084, 256, 0, stream>>>(pat, amax, plane);
  k_reduce<<<400, 256, 0, stream>>>(plane, out);
}

// Round 10
// 420.039 us; speedup vs baseline: 1.0526x; 1.0526x over previous
//
#include <hip/hip_runtime.h>
#include <stdint.h>

#define NPIX 6084      // 78*78 pixels / patches
#define NPAD 6144      // padded to 48*128 (= 24*256)
#define KDIM 2304      // 256*3*3
#define KB   (KDIM*2)  // row bytes in bf16 = 4608
#define NT   36        // K-tiles of 64

typedef __attribute__((ext_vector_type(8))) short s16x8;
typedef __attribute__((ext_vector_type(4))) float f32x4;

__device__ __forceinline__ short f2bf(float f) {
  unsigned u = __builtin_bit_cast(unsigned, f);
  u += 0x7FFFu + ((u >> 16) & 1u);
  return (short)(u >> 16);
}
__device__ __forceinline__ float bf2f(short s) {
  unsigned u = ((unsigned)(unsigned short)s) << 16;
  return __builtin_bit_cast(float, u);
}

#define GL16(g, l)                                                            \
  __builtin_amdgcn_global_load_lds(                                           \
      (__attribute__((address_space(1))) unsigned int*)(g),                   \
      (__attribute__((address_space(3))) unsigned int*)(l), 16, 0, 0)

// ---------------- prep: cast patches f32 -> bf16, pad rows to 6144 ----------
__global__ __launch_bounds__(256) void k_prep_pat(const float* __restrict__ pat,
                                                  short* __restrict__ out) {
  int i = blockIdx.x * 256 + threadIdx.x;  // one 8-elem chunk
  int e0 = i * 8;
  int row = e0 / KDIM;
  s16x8 v;
  if (row < NPIX) {
    const float* s = pat + e0;
#pragma unroll
    for (int j = 0; j < 8; ++j) v[j] = f2bf(s[j]);
  } else {
#pragma unroll
    for (int j = 0; j < 8; ++j) v[j] = 0;
  }
  *(s16x8*)(out + e0) = v;
}

// ------- im2col v2: LDS-staged, coalesced reads AND writes ------------------
__global__ __launch_bounds__(256) void k_xcol2(const float* __restrict__ x,
                                               short* __restrict__ out) {
  __shared__ float lx[7680];  // [32 ch][3 rows][80 cols]
  const int b = blockIdx.x, tid = threadIdx.x;
  if (b >= 624) {  // zero pad rows
    int i = b - 624;
    s16x8 z = {};
#pragma unroll
    for (int it = 0; it < 9; ++it) {
      int t = i * 2160 + it * 256 + tid;  // 8*2160 = 17280 chunks exactly
      if (t < 17280) ((s16x8*)out)[(size_t)NPIX * KDIM / 8 + t] = z;
    }
    return;
  }
  const int p = b >> 3, cc = b & 7;
  for (int t = tid; t < 7680; t += 256) {
    int ci = t / 240, rr = t - ci * 240;
    lx[t] = x[(cc * 32 + ci) * 6400 + p * 80 + rr];
  }
  __syncthreads();
  for (int t = tid; t < 22464; t += 256) {  // 78 q * 288 e
    int q = t / 288, e = t - q * 288;
    int ci = e / 9, r = e - ci * 9;
    int dy = r / 3, dx = r - dy * 3;
    out[(size_t)(p * 78 + q) * KDIM + cc * 288 + e] =
        f2bf(lx[ci * 240 + dy * 80 + q + dx]);
  }
}

// ---------------- GEMM: 256x256 tile, BK=64, 8-phase counted-vmcnt ----------
// EXACT round-8 version (191 us, MfmaUtil 39, bank-conflict 0): T3+T4
// (vmcnt(6) at P4/P8 only) + T2 (3-bit XOR swizzle) + T5 (setprio). Barriers
// are asm s_barrier with "memory" clobber; GL16 dest is wave-uniform base.
// Epilogue does ONLY the sim write (row-max fusion regressed it 191->243:
// identical MFMA cycles, +52us epilogue/codegen cost at 1 block/CU).
__global__ __launch_bounds__(512, 2) void k_gemm(const short* __restrict__ A,
                                                 const short* __restrict__ B,
                                                 short* __restrict__ C) {
  __shared__ __align__(1024) char smem[131072];  // [par][A 32K | B 32K]
  const int tid = threadIdx.x;
  const int w = tid >> 6, lane = tid & 63;
  const int wr = w >> 2, wc = w & 3;  // 2M x 4N
  const int tm = blockIdx.y, tn = blockIdx.x;
  const char* Ab = (const char*)A + (size_t)tm * 256 * KB;
  const char* Bb = (const char*)B + (size_t)tn * 256 * KB;

  const int srccol = ((lane & 7) * 16) ^ ((lane >> 3) << 4);
  const int lrow = lane >> 3;
  const int fragRow = lane & 15;
  const int swz = (lane & 7) << 4;
  const int colb0 = (lane >> 4) * 16;
  const int aOff = (wr * 128 + fragRow) * 128;
  const int bOff = 32768 + (wc * 64 + fragRow) * 128;

  f32x4 acc[8][4] = {};
  s16x8 a[4][2];
  s16x8 b[2][2][2];

#define STAGE_A(par, hs, kt)                                                  \
  _Pragma("unroll") for (int j = 0; j < 2; ++j) {                             \
    int c = w * 2 + j;                                                        \
    int rb = (c < 8) ? (hs)*64 + c * 8 : 128 + (hs)*64 + (c - 8) * 8;         \
    GL16(Ab + (size_t)(rb + lrow) * KB + (kt)*128 + srccol,                   \
         smem + (par)*65536 + rb * 128);                                      \
  }
#define STAGE_B(par, hs, kt)                                                  \
  _Pragma("unroll") for (int j = 0; j < 2; ++j) {                             \
    int c = w * 2 + j;                                                        \
    int rb = (c >> 2) * 64 + (hs)*32 + (c & 3) * 8;                           \
    GL16(Bb + (size_t)(rb + lrow) * KB + (kt)*128 + srccol,                   \
         smem + (par)*65536 + 32768 + rb * 128);                              \
  }
#define LDA(par, mh)                                                          \
  _Pragma("unroll") for (int mi2 = 0; mi2 < 4; ++mi2)                         \
  _Pragma("unroll") for (int ks = 0; ks < 2; ++ks)                            \
    a[mi2][ks] = *(const s16x8*)(smem + (par)*65536 + aOff + (mh)*8192 +      \
                                 mi2 * 2048 + ((colb0 + ks * 64) ^ swz));
#define LDB(par, nh)                                                          \
  _Pragma("unroll") for (int ni2 = 0; ni2 < 2; ++ni2)                         \
  _Pragma("unroll") for (int ks = 0; ks < 2; ++ks)                            \
    b[nh][ni2][ks] = *(const s16x8*)(smem + (par)*65536 + bOff + (nh)*4096 +  \
                                     ni2 * 2048 + ((colb0 + ks * 64) ^ swz));
#define VM6() asm volatile("s_waitcnt vmcnt(6)" ::: "memory")
#define BAR() asm volatile("s_barrier" ::: "memory")
#define BARL() asm volatile("s_barrier\n\ts_waitcnt lgkmcnt(0)" ::: "memory")
#define QM(mh, nh)                                                            \
  do {                                                                        \
    __builtin_amdgcn_s_setprio(1);                                            \
    _Pragma("unroll") for (int mi2 = 0; mi2 < 4; ++mi2)                       \
    _Pragma("unroll") for (int ni2 = 0; ni2 < 2; ++ni2)                       \
    _Pragma("unroll") for (int ks = 0; ks < 2; ++ks)                          \
      acc[(mh)*4 + mi2][(nh)*2 + ni2] =                                       \
          __builtin_amdgcn_mfma_f32_16x16x32_bf16(                            \
              a[mi2][ks], b[nh][ni2][ks], acc[(mh)*4 + mi2][(nh)*2 + ni2],    \
              0, 0, 0);                                                       \
    __builtin_amdgcn_s_setprio(0);                                            \
    BAR();                                                                    \
  } while (0)

  STAGE_A(0, 0, 0); STAGE_B(0, 0, 0); STAGE_B(0, 1, 0); STAGE_A(0, 1, 0);
  STAGE_A(1, 0, 1); STAGE_B(1, 0, 1); STAGE_B(1, 1, 1);
  VM6();
  BAR();

#pragma unroll 1
  for (int i = 0; i < NT / 2; ++i) {
    const int t2 = (2 * i + 2 < NT) ? 2 * i + 2 : NT - 1;
    const int t3 = (2 * i + 3 < NT) ? 2 * i + 3 : NT - 1;
    LDA(0, 0); LDB(0, 0);
    STAGE_A(1, 1, 2 * i + 1);
    BARL(); QM(0, 0);
    LDB(0, 1);
    STAGE_A(0, 0, t2);
    BARL(); QM(0, 1);
    LDA(0, 1);
    STAGE_B(0, 0, t2);
    BARL(); QM(1, 1);
    STAGE_B(0, 1, t2);
    VM6();
    BARL(); QM(1, 0);
    LDA(1, 0); LDB(1, 0);
    STAGE_A(0, 1, t2);
    BARL(); QM(0, 0);
    LDB(1, 1);
    STAGE_A(1, 0, t3);
    BARL(); QM(0, 1);
    LDA(1, 1);
    STAGE_B(1, 0, t3);
    BARL(); QM(1, 1);
    STAGE_B(1, 1, t3);
    VM6();
    BARL(); QM(1, 0);
  }

  // epilogue: write bf16 sim
  const int rowb = tm * 256 + wr * 128 + (lane >> 4) * 4;
  const int colb = tn * 256 + wc * 64 + (lane & 15);
#pragma unroll
  for (int mi = 0; mi < 8; ++mi)
#pragma unroll
    for (int ni = 0; ni < 4; ++ni)
#pragma unroll
      for (int j = 0; j < 4; ++j)
        C[(size_t)(rowb + mi * 16 + j) * NPAD + colb + ni * 16] =
            f2bf(acc[mi][ni][j]);
}

// ------- rowmax: per-(row, 256-col segment) max + argcol from sim -----------
// One wave per row; 12 passes of s16x8 (512 cols = 2 segments/pass); per-half
// shfl reduce. Same tie rule as always: max value, lowest col.
__global__ __launch_bounds__(256) void k_rowmax(const short* __restrict__ sim,
                                                float* __restrict__ gval,
                                                int* __restrict__ gidx) {
  const int tid = threadIdx.x, w = tid >> 6, lane = tid & 63;
  const int row = blockIdx.x * 4 + w;  // 1521*4 = 6084 exact
  const short* r = sim + (size_t)row * NPAD;
#pragma unroll 1
  for (int p = 0; p < 12; ++p) {
    int c0 = p * 512 + lane * 8;
    s16x8 v = *(const s16x8*)(r + c0);
    float bv = -1e30f;
    int bc = 0x7FFFFFFF;
#pragma unroll
    for (int j = 0; j < 8; ++j) {
      int k = c0 + j;
      float f = bf2f(v[j]);
      if (k < NPIX && (f > bv || (f == bv && k < bc))) { bv = f; bc = k; }
    }
#pragma unroll
    for (int off = 1; off < 32; off <<= 1) {  // stays within 32-lane halves
      float ov = __shfl_xor(bv, off);
      int oc = __shfl_xor(bc, off);
      if (ov > bv || (ov == bv && oc < bc)) { bv = ov; bc = oc; }
    }
    if ((lane & 31) == 0) {
      int seg = p * 2 + (lane >> 5);
      gval[seg * NPAD + row] = bv;
      gidx[seg * NPAD + row] = bc;
    }
  }
}

// ------- argmax v2: reduce 24 block-maxes, lazy sim read, f64 rescore -------
__global__ __launch_bounds__(256) void k_argmax2(const short* __restrict__ sim,
                                                 const float* __restrict__ gval,
                                                 const int* __restrict__ gidx,
                                                 const float* __restrict__ x,
                                                 const float* __restrict__ pat,
                                                 int* __restrict__ amax) {
  __shared__ int cand[4][32];
  __shared__ int ccnt[4];
  const int tid = threadIdx.x, w = tid >> 6, lane = tid & 63;
  const int pix = blockIdx.x * 4 + w;  // 1521*4 = 6084 exact

  float v0 = (lane < 24) ? gval[lane * NPAD + pix] : -1e30f;
  int c0 = (lane < 24) ? gidx[lane * NPAD + pix] : 0x7FFFFFFF;
  float v = v0;
  int c = c0;
  for (int off = 32; off; off >>= 1) {
    float ov = __shfl_down(v, off);
    int oc = __shfl_down(c, off);
    if (ov > v || (ov == v && oc < c)) { v = ov; c = oc; }
  }
  const float maxv = __shfl(v, 0);
  const int bestc = __shfl(c, 0);

  if (lane == 0) ccnt[w] = 0;
  __syncthreads();

  const float thrb = maxv - 4.0f;
  for (int t = 0; t < 24; ++t) {
    float bm = __shfl(v0, t);
    if (bm >= thrb) {
      short4 s4 = *(const short4*)(sim + (size_t)pix * NPAD + t * 256 + lane * 4);
#pragma unroll
      for (int j = 0; j < 4; ++j) {
        int k = t * 256 + lane * 4 + j;
        float f = bf2f(((const short*)&s4)[j]);
        if (f >= thrb - 0.6f && k < NPIX) {
          int pos = atomicAdd(&ccnt[w], 1);
          if (pos < 32) cand[w][pos] = k;
        }
      }
    }
  }
  __syncthreads();

  int n = ccnt[w] < 32 ? ccnt[w] : 32;
  if (n <= 1) {
    if (lane == 0) amax[pix] = bestc;
    return;
  }
  const int p = pix / 78, q = pix - (pix / 78) * 78;
  double bests = -1e300;
  int bestk = 0;
  for (int ci = 0; ci < n; ++ci) {
    int k = cand[w][ci];
    double s = 0.0;
    for (int cc = lane; cc < 256; cc += 64) {
      const float* xb = x + cc * 6400 + p * 80 + q;
      const float* pb = pat + (size_t)k * KDIM + cc * 9;
#pragma unroll
      for (int dy = 0; dy < 3; ++dy)
#pragma unroll
        for (int dx = 0; dx < 3; ++dx)
          s += (double)xb[dy * 80 + dx] * (double)pb[dy * 3 + dx];
    }
    for (int off = 32; off; off >>= 1) s += __shfl_down(s, off);
    if (lane == 0 && (s > bests || (s == bests && k < bestk))) {
      bests = s; bestk = k;
    }
  }
  if (lane == 0) amax[pix] = bestk;
}

// ------- scatter9: collision-free scatter into 9 shift planes ---------------
__global__ __launch_bounds__(256) void k_scat9(const float* __restrict__ pat,
                                               const int* __restrict__ amax,
                                               float* __restrict__ plane) {
  __shared__ float lp[KDIM];
  const int b = blockIdx.x;            // 6084 source pixels
  const int k = amax[b];
  const int p = b / 78, q = b - (b / 78) * 78;
  const float* src = pat + (size_t)k * KDIM;
#pragma unroll
  for (int j = 0; j < 9; ++j) lp[j * 256 + threadIdx.x] = src[j * 256 + threadIdx.x];
  __syncthreads();
  const int c = threadIdx.x;
#pragma unroll
  for (int r = 0; r < 9; ++r) {
    int dy = r / 3, dx = r - dy * 3;
    int pos = (p + dy) * 80 + (q + dx);   // always in [0,6400)
    plane[(size_t)r * 1638400 + pos * 256 + c] = lp[c * 9 + r];
  }
}

// ------- reduce: out[c][pix] = sum over valid planes / analytic count -------
__global__ __launch_bounds__(256) void k_reduce(const float* __restrict__ plane,
                                                float* __restrict__ out) {
  const int c = threadIdx.x;
  const int pix0 = blockIdx.x * 16;
  for (int i = 0; i < 16; ++i) {
    int pix = pix0 + i;
    int yy = pix / 80, xx = pix - (pix / 80) * 80;
    float s = 0.f;
    int cnt = 0;
#pragma unroll
    for (int r = 0; r < 9; ++r) {
      int dy = r / 3, dx = r - dy * 3;
      int p = yy - dy, q = xx - dx;
      if (p >= 0 && p < 78 && q >= 0 && q < 78) {
        s += plane[(size_t)r * 1638400 + pix * 256 + c];
        ++cnt;
      }
    }
    out[c * 6400 + pix] = s / (float)cnt;
  }
}

extern "C" void kernel_launch(void* const* d_in, const int* in_sizes, int n_in,
                              void* d_out, int out_size, void* d_ws,
                              size_t ws_size, hipStream_t stream) {
  const float* x = (const float*)d_in[0];    // (1,256,80,80) f32
  const float* pat = (const float*)d_in[1];  // (6084,256,3,3) f32
  float* out = (float*)d_out;                // (1,256,80,80) f32
  char* ws = (char*)d_ws;

  short* patB = (short*)ws;                          // 28,311,552 B
  short* xcol = (short*)(ws + 28311552);             // 28,311,552 B
  short* sim  = (short*)(ws + 2 * 28311552);         // 75,497,472 B
  float* plane = (float*)sim;                        // 58,982,400 B (overlays dead sim)
  int*   amax = (int*)(ws + 132120576);              // 24,336 B
  float* gval = (float*)(ws + 132144912);            // 589,824 B
  int*   gidx = (int*)(ws + 132734736);              // 589,824 B (ends 127.2 MiB)

  k_prep_pat<<<6912, 256, 0, stream>>>(pat, patB);
  k_xcol2<<<632, 256, 0, stream>>>(x, xcol);
  k_gemm<<<dim3(24, 24), 512, 0, stream>>>(xcol, patB, sim);
  k_rowmax<<<1521, 256, 0, stream>>>(sim, gval, gidx);
  k_argmax2<<<1521, 256, 0, stream>>>(sim, gval, gidx, x, pat, amax);
  k_scat9<<<6084, 256, 0, stream>>>(pat, amax, plane);
  k_reduce<<<400, 256, 0, stream>>>(plane, out);
}

// Round 12
// 403.509 us; speedup vs baseline: 1.0957x; 1.0410x over previous
//
#include <hip/hip_runtime.h>
#include <stdint.h>

#define NPIX 6084      // 78*78 pixels / patches
#define NPAD 6144      // padded to 48*128 (= 24*256)
#define KDIM 2304      // 256*3*3
#define KB   (KDIM*2)  // row bytes in bf16 = 4608
#define NT   36        // K-tiles of 64

typedef __attribute__((ext_vector_type(8))) short s16x8;
typedef __attribute__((ext_vector_type(4))) float f32x4;

__device__ __forceinline__ short f2bf(float f) {
  unsigned u = __builtin_bit_cast(unsigned, f);
  u += 0x7FFFu + ((u >> 16) & 1u);
  return (short)(u >> 16);
}
__device__ __forceinline__ float bf2f(short s) {
  unsigned u = ((unsigned)(unsigned short)s) << 16;
  return __builtin_bit_cast(float, u);
}

#define GL16(g, l)                                                            \
  __builtin_amdgcn_global_load_lds(                                           \
      (__attribute__((address_space(1))) unsigned int*)(g),                   \
      (__attribute__((address_space(3))) unsigned int*)(l), 16, 0, 0)

// ------- prep (fused): blocks [0,6912) cast patches; [6912,7544) im2col -----
__global__ __launch_bounds__(256) void k_prep(const float* __restrict__ pat,
                                              const float* __restrict__ x,
                                              short* __restrict__ patB,
                                              short* __restrict__ xcol) {
  __shared__ float lx[7680];  // [32 ch][3 rows][80 cols] (xcol branch only)
  const int b = blockIdx.x, tid = threadIdx.x;
  if (b < 6912) {  // ---- patches f32 -> bf16, pad rows to 6144
    int e0 = (b * 256 + tid) * 8;
    int row = e0 / KDIM;
    s16x8 v;
    if (row < NPIX) {
      const float* s = pat + e0;
#pragma unroll
      for (int j = 0; j < 8; ++j) v[j] = f2bf(s[j]);
    } else {
#pragma unroll
      for (int j = 0; j < 8; ++j) v[j] = 0;
    }
    *(s16x8*)(patB + e0) = v;
    return;
  }
  const int bb = b - 6912;
  if (bb >= 624) {  // ---- zero xcol pad rows
    int i = bb - 624;
    s16x8 z = {};
#pragma unroll
    for (int it = 0; it < 9; ++it) {
      int t = i * 2160 + it * 256 + tid;
      if (t < 17280) ((s16x8*)xcol)[(size_t)NPIX * KDIM / 8 + t] = z;
    }
    return;
  }
  const int p = bb >> 3, cc = bb & 7;  // ---- im2col, LDS-staged
  for (int t = tid; t < 7680; t += 256) {
    int ci = t / 240, rr = t - ci * 240;
    lx[t] = x[(cc * 32 + ci) * 6400 + p * 80 + rr];
  }
  __syncthreads();
  for (int t = tid; t < 22464; t += 256) {  // 78 q * 288 e
    int q = t / 288, e = t - q * 288;
    int ci = e / 9, r = e - ci * 9;
    int dy = r / 3, dx = r - dy * 3;
    xcol[(size_t)(p * 78 + q) * KDIM + cc * 288 + e] =
        f2bf(lx[ci * 240 + dy * 80 + q + dx]);
  }
}

// ---------------- GEMM: 256x256 tile, BK=64, 8-phase counted-vmcnt ----------
// EXACT round-8/10 version (190 us, MfmaUtil 39, bank-conflict 0). T3+T4
// (vmcnt(6) at P4/P8 only) + T2 (3-bit XOR swizzle) + T5 (setprio). Barriers
// are asm s_barrier with "memory" clobber; GL16 dest is wave-uniform base.
__global__ __launch_bounds__(512, 2) void k_gemm(const short* __restrict__ A,
                                                 const short* __restrict__ B,
                                                 short* __restrict__ C) {
  __shared__ __align__(1024) char smem[131072];  // [par][A 32K | B 32K]
  const int tid = threadIdx.x;
  const int w = tid >> 6, lane = tid & 63;
  const int wr = w >> 2, wc = w & 3;  // 2M x 4N
  const int tm = blockIdx.y, tn = blockIdx.x;
  const char* Ab = (const char*)A + (size_t)tm * 256 * KB;
  const char* Bb = (const char*)B + (size_t)tn * 256 * KB;

  const int srccol = ((lane & 7) * 16) ^ ((lane >> 3) << 4);
  const int lrow = lane >> 3;
  const int fragRow = lane & 15;
  const int swz = (lane & 7) << 4;
  const int colb0 = (lane >> 4) * 16;
  const int aOff = (wr * 128 + fragRow) * 128;
  const int bOff = 32768 + (wc * 64 + fragRow) * 128;

  f32x4 acc[8][4] = {};
  s16x8 a[4][2];
  s16x8 b[2][2][2];

#define STAGE_A(par, hs, kt)                                                  \
  _Pragma("unroll") for (int j = 0; j < 2; ++j) {                             \
    int c = w * 2 + j;                                                        \
    int rb = (c < 8) ? (hs)*64 + c * 8 : 128 + (hs)*64 + (c - 8) * 8;         \
    GL16(Ab + (size_t)(rb + lrow) * KB + (kt)*128 + srccol,                   \
         smem + (par)*65536 + rb * 128);                                      \
  }
#define STAGE_B(par, hs, kt)                                                  \
  _Pragma("unroll") for (int j = 0; j < 2; ++j) {                             \
    int c = w * 2 + j;                                                        \
    int rb = (c >> 2) * 64 + (hs)*32 + (c & 3) * 8;                           \
    GL16(Bb + (size_t)(rb + lrow) * KB + (kt)*128 + srccol,                   \
         smem + (par)*65536 + 32768 + rb * 128);                              \
  }
#define LDA(par, mh)                                                          \
  _Pragma("unroll") for (int mi2 = 0; mi2 < 4; ++mi2)                         \
  _Pragma("unroll") for (int ks = 0; ks < 2; ++ks)                            \
    a[mi2][ks] = *(const s16x8*)(smem + (par)*65536 + aOff + (mh)*8192 +      \
                                 mi2 * 2048 + ((colb0 + ks * 64) ^ swz));
#define LDB(par, nh)                                                          \
  _Pragma("unroll") for (int ni2 = 0; ni2 < 2; ++ni2)                         \
  _Pragma("unroll") for (int ks = 0; ks < 2; ++ks)                            \
    b[nh][ni2][ks] = *(const s16x8*)(smem + (par)*65536 + bOff + (nh)*4096 +  \
                                     ni2 * 2048 + ((colb0 + ks * 64) ^ swz));
#define VM6() asm volatile("s_waitcnt vmcnt(6)" ::: "memory")
#define BAR() asm volatile("s_barrier" ::: "memory")
#define BARL() asm volatile("s_barrier\n\ts_waitcnt lgkmcnt(0)" ::: "memory")
#define QM(mh, nh)                                                            \
  do {                                                                        \
    __builtin_amdgcn_s_setprio(1);                                            \
    _Pragma("unroll") for (int mi2 = 0; mi2 < 4; ++mi2)                       \
    _Pragma("unroll") for (int ni2 = 0; ni2 < 2; ++ni2)                       \
    _Pragma("unroll") for (int ks = 0; ks < 2; ++ks)                          \
      acc[(mh)*4 + mi2][(nh)*2 + ni2] =                                       \
          __builtin_amdgcn_mfma_f32_16x16x32_bf16(                            \
              a[mi2][ks], b[nh][ni2][ks], acc[(mh)*4 + mi2][(nh)*2 + ni2],    \
              0, 0, 0);                                                       \
    __builtin_amdgcn_s_setprio(0);                                            \
    BAR();                                                                    \
  } while (0)

  STAGE_A(0, 0, 0); STAGE_B(0, 0, 0); STAGE_B(0, 1, 0); STAGE_A(0, 1, 0);
  STAGE_A(1, 0, 1); STAGE_B(1, 0, 1); STAGE_B(1, 1, 1);
  VM6();
  BAR();

#pragma unroll 1
  for (int i = 0; i < NT / 2; ++i) {
    const int t2 = (2 * i + 2 < NT) ? 2 * i + 2 : NT - 1;
    const int t3 = (2 * i + 3 < NT) ? 2 * i + 3 : NT - 1;
    LDA(0, 0); LDB(0, 0);
    STAGE_A(1, 1, 2 * i + 1);
    BARL(); QM(0, 0);
    LDB(0, 1);
    STAGE_A(0, 0, t2);
    BARL(); QM(0, 1);
    LDA(0, 1);
    STAGE_B(0, 0, t2);
    BARL(); QM(1, 1);
    STAGE_B(0, 1, t2);
    VM6();
    BARL(); QM(1, 0);
    LDA(1, 0); LDB(1, 0);
    STAGE_A(0, 1, t2);
    BARL(); QM(0, 0);
    LDB(1, 1);
    STAGE_A(1, 0, t3);
    BARL(); QM(0, 1);
    LDA(1, 1);
    STAGE_B(1, 0, t3);
    BARL(); QM(1, 1);
    STAGE_B(1, 1, t3);
    VM6();
    BARL(); QM(1, 0);
  }

  // epilogue: write bf16 sim
  const int rowb = tm * 256 + wr * 128 + (lane >> 4) * 4;
  const int colb = tn * 256 + wc * 64 + (lane & 15);
#pragma unroll
  for (int mi = 0; mi < 8; ++mi)
#pragma unroll
    for (int ni = 0; ni < 4; ++ni)
#pragma unroll
      for (int j = 0; j < 4; ++j)
        C[(size_t)(rowb + mi * 16 + j) * NPAD + colb + ni * 16] =
            f2bf(acc[mi][ni][j]);
}

// ------- rowargmax (fused rowmax + lazy candidates + f64 rescore) -----------
// 4 waves = 4 rows per block. Pass 1: one coalesced scan -> row max (tie:
// lowest k) + 24 segment maxes. Pass 2: re-read only segments >= max-4
// (L2-hot) to collect candidates. Rescore in f64 when >1 candidate.
__global__ __launch_bounds__(256) void k_rowargmax(const short* __restrict__ sim,
                                                   const float* __restrict__ x,
                                                   const float* __restrict__ pat,
                                                   int* __restrict__ amax) {
  __shared__ float segmax[4][24];
  __shared__ int cand[4][32];
  __shared__ int ccnt[4];
  const int tid = threadIdx.x, w = tid >> 6, lane = tid & 63;
  const int pix = blockIdx.x * 4 + w;  // 1521*4 = 6084 exact
  const short* row = sim + (size_t)pix * NPAD;

  float bv = -1e30f;  // lane-persistent overall best
  int bc = 0x7FFFFFFF;
#pragma unroll 1
  for (int p = 0; p < 12; ++p) {
    int c0 = p * 512 + lane * 8;
    s16x8 v = *(const s16x8*)(row + c0);
    float sb = -1e30f;  // this pass (one segment per 32-lane half)
    int sc = 0x7FFFFFFF;
#pragma unroll
    for (int j = 0; j < 8; ++j) {
      int k = c0 + j;
      float f = bf2f(v[j]);
      if (k < NPIX && (f > sb || (f == sb && k < sc))) { sb = f; sc = k; }
    }
    if (sb > bv || (sb == bv && sc < bc)) { bv = sb; bc = sc; }
#pragma unroll
    for (int off = 1; off < 32; off <<= 1) {  // within 32-lane halves
      float ov = __shfl_xor(sb, off);
      if (ov > sb) sb = ov;
    }
    if ((lane & 31) == 0) segmax[w][p * 2 + (lane >> 5)] = sb;
  }
#pragma unroll
  for (int off = 1; off < 64; off <<= 1) {  // full-wave, tie-lowest
    float ov = __shfl_xor(bv, off);
    int oc = __shfl_xor(bc, off);
    if (ov > bv || (ov == bv && oc < bc)) { bv = ov; bc = oc; }
  }
  const float maxv = bv;
  const int bestc = bc;

  if (lane == 0) ccnt[w] = 0;
  __syncthreads();

  const float thr = maxv - 4.0f;
#pragma unroll 1
  for (int seg = 0; seg < 24; ++seg) {
    if (segmax[w][seg] >= thr) {
      short4 s4 = *(const short4*)(row + seg * 256 + lane * 4);
#pragma unroll
      for (int j = 0; j < 4; ++j) {
        int k = seg * 256 + lane * 4 + j;
        float f = bf2f(((const short*)&s4)[j]);
        if (f >= thr && k < NPIX) {
          int pos = atomicAdd(&ccnt[w], 1);
          if (pos < 32) cand[w][pos] = k;
        }
      }
    }
  }
  __syncthreads();

  int n = ccnt[w] < 32 ? ccnt[w] : 32;
  if (n <= 1) {
    if (lane == 0) amax[pix] = bestc;
    return;
  }
  const int p = pix / 78, q = pix - (pix / 78) * 78;
  double bests = -1e300;
  int bestk = 0;
  for (int ci = 0; ci < n; ++ci) {
    int k = cand[w][ci];
    double s = 0.0;
    for (int cc = lane; cc < 256; cc += 64) {
      const float* xb = x + cc * 6400 + p * 80 + q;
      const float* pb = pat + (size_t)k * KDIM + cc * 9;
#pragma unroll
      for (int dy = 0; dy < 3; ++dy)
#pragma unroll
        for (int dx = 0; dx < 3; ++dx)
          s += (double)xb[dy * 80 + dx] * (double)pb[dy * 3 + dx];
    }
    for (int off = 32; off; off >>= 1) s += __shfl_down(s, off);
    if (lane == 0 && (s > bests || (s == bests && k < bestk))) {
      bests = s; bestk = k;
    }
  }
  if (lane == 0) amax[pix] = bestk;
}

// ------- scatter9: collision-free scatter into 9 bf16 shift planes ----------
__global__ __launch_bounds__(256) void k_scat9(const float* __restrict__ pat,
                                               const int* __restrict__ amax,
                                               short* __restrict__ plane) {
  __shared__ float lp[KDIM];
  const int b = blockIdx.x;            // 6084 source pixels
  const int k = amax[b];
  const int p = b / 78, q = b - (b / 78) * 78;
  const float* src = pat + (size_t)k * KDIM;
#pragma unroll
  for (int j = 0; j < 9; ++j) lp[j * 256 + threadIdx.x] = src[j * 256 + threadIdx.x];
  __syncthreads();
  const int c = threadIdx.x;
#pragma unroll
  for (int r = 0; r < 9; ++r) {
    int dy = r / 3, dx = r - dy * 3;
    int pos = (p + dy) * 80 + (q + dx);   // always in [0,6400)
    plane[(size_t)r * 1638400 + pos * 256 + c] = f2bf(lp[c * 9 + r]);
  }
}

// ------- reduce: out[c][pix] = sum over valid bf16 planes / count -----------
__global__ __launch_bounds__(256) void k_reduce(const short* __restrict__ plane,
                                                float* __restrict__ out) {
  const int c = threadIdx.x;
  const int pix0 = blockIdx.x * 16;
  for (int i = 0; i < 16; ++i) {
    int pix = pix0 + i;
    int yy = pix / 80, xx = pix - (pix / 80) * 80;
    float s = 0.f;
    int cnt = 0;
#pragma unroll
    for (int r = 0; r < 9; ++r) {
      int dy = r / 3, dx = r - dy * 3;
      int p = yy - dy, q = xx - dx;
      if (p >= 0 && p < 78 && q >= 0 && q < 78) {
        s += bf2f(plane[(size_t)r * 1638400 + pix * 256 + c]);
        ++cnt;
      }
    }
    out[c * 6400 + pix] = s / (float)cnt;
  }
}

extern "C" void kernel_launch(void* const* d_in, const int* in_sizes, int n_in,
                              void* d_out, int out_size, void* d_ws,
                              size_t ws_size, hipStream_t stream) {
  const float* x = (const float*)d_in[0];    // (1,256,80,80) f32
  const float* pat = (const float*)d_in[1];  // (6084,256,3,3) f32
  float* out = (float*)d_out;                // (1,256,80,80) f32
  char* ws = (char*)d_ws;

  short* patB = (short*)ws;                          // 28,311,552 B
  short* xcol = (short*)(ws + 28311552);             // 28,311,552 B
  short* sim  = (short*)(ws + 2 * 28311552);         // 75,497,472 B
  short* plane = sim;                                // 29,491,200 B (overlays dead sim)
  int*   amax = (int*)(ws + 132120576);              // 24,336 B

  k_prep<<<7544, 256, 0, stream>>>(pat, x, patB, xcol);
  k_gemm<<<dim3(24, 24), 512, 0, stream>>>(xcol, patB, sim);
  k_rowargmax<<<1521, 256, 0, stream>>>(sim, x, pat, amax);
  k_scat9<<<6084, 256, 0, stream>>>(pat, amax, plane);
  k_reduce<<<400, 256, 0, stream>>>(plane, out);
}